// Round 6
// baseline (193.870 us; speedup 1.0000x reference)
//
#include <hip/hip_runtime.h>
#include <stdint.h>

typedef unsigned short u16;
typedef unsigned int u32;
typedef short bf16x8 __attribute__((ext_vector_type(8)));
typedef float f32x4 __attribute__((ext_vector_type(4)));

#define K_DIM 512

__device__ __forceinline__ u16 f2bf(float f) {
  union { float f; u32 u; } v; v.f = f;
  return (u16)((v.u + 0x8000u) >> 16);  // round-half-up
}
__device__ __forceinline__ u32 pk2(float lo, float hi) {
  union { float f; u32 u; } a, b; a.f = lo; b.f = hi;
  return __builtin_amdgcn_perm(b.u + 0x8000u, a.u + 0x8000u, 0x07060302u);
}
__device__ __forceinline__ uint4 pk8(const float4& a, const float4& b) {
  return make_uint4(pk2(a.x, a.y), pk2(a.z, a.w), pk2(b.x, b.y), pk2(b.z, b.w));
}

#define LDA 40  // BK=32 + 8 pad (stride mult of 8 u16 keeps b128 alignment)

// ---------------- kernel 1: QKV GEMM, fp32 inputs fused-converted, C^T epilogue ----------------
// Logical A row m in [0,8192): m<4096 -> x1 row m, else x2 row m-4096.
// f = h*192 + s*64 + d. q scaled by (1/8)*log2(e); q/k layout [in,b,h,l,d]; v transposed [in,b,h,d,l].
__global__ __launch_bounds__(256, 3) void qkv_gemm(
    const float* __restrict__ X1, const float* __restrict__ X2,
    const float* __restrict__ W, const float* __restrict__ bias,
    u16* __restrict__ qb, u16* __restrict__ kb, u16* __restrict__ vtb) {
  __shared__ __align__(16) u16 As[128 * LDA];
  __shared__ __align__(16) u16 Bs[128 * LDA];
  const int t = threadIdx.x;
  const int m0 = blockIdx.x * 128, n0 = blockIdx.y * 128;
  const int lane = t & 63, l16 = lane & 15, quad = lane >> 4;
  const int w = t >> 6;
  const int wm = (w >> 1) * 64, wn = (w & 1) * 64;

  const float* A = (m0 < 4096) ? X1 : X2;
  const int mrow = m0 & 4095;

  const int srow = t >> 1, sc0 = (t & 1) * 16;
  const float* Apf = A + (size_t)(mrow + srow) * K_DIM + sc0;
  const float* Wpf = W + (size_t)(n0 + srow) * K_DIM + sc0;

  f32x4 acc[4][4];
#pragma unroll
  for (int i = 0; i < 4; ++i)
#pragma unroll
    for (int j = 0; j < 4; ++j) acc[i][j] = (f32x4){0.f, 0.f, 0.f, 0.f};

  float4 a4[4], w4[4];
#pragma unroll
  for (int j = 0; j < 4; ++j) {
    a4[j] = ((const float4*)Apf)[j];
    w4[j] = ((const float4*)Wpf)[j];
  }

  for (int kt = 0; kt < 16; ++kt) {
    *(uint4*)&As[srow * LDA + sc0]     = pk8(a4[0], a4[1]);
    *(uint4*)&As[srow * LDA + sc0 + 8] = pk8(a4[2], a4[3]);
    *(uint4*)&Bs[srow * LDA + sc0]     = pk8(w4[0], w4[1]);
    *(uint4*)&Bs[srow * LDA + sc0 + 8] = pk8(w4[2], w4[3]);
    __syncthreads();
    if (kt < 15) {
      int ko = (kt + 1) * 32;
#pragma unroll
      for (int j = 0; j < 4; ++j) {
        a4[j] = ((const float4*)(Apf + ko))[j];
        w4[j] = ((const float4*)(Wpf + ko))[j];
      }
    }
    bf16x8 af[4], bfr[4];
#pragma unroll
    for (int mi = 0; mi < 4; ++mi)
      af[mi] = *(const bf16x8*)&As[(wm + mi * 16 + l16) * LDA + quad * 8];
#pragma unroll
    for (int ni = 0; ni < 4; ++ni)
      bfr[ni] = *(const bf16x8*)&Bs[(wn + ni * 16 + l16) * LDA + quad * 8];
    // SWAPPED operands: C^T -> row(quad,r)=f-offset, col(l16)=m-offset
#pragma unroll
    for (int mi = 0; mi < 4; ++mi)
#pragma unroll
      for (int ni = 0; ni < 4; ++ni)
        acc[mi][ni] = __builtin_amdgcn_mfma_f32_16x16x32_bf16(bfr[ni], af[mi], acc[mi][ni], 0, 0, 0);
    __syncthreads();
  }

  const int fbase = n0 + wn;
  const int h = fbase / 192;
  const int s = (fbase - h * 192) >> 6;
  float4 bv[4];
#pragma unroll
  for (int ni = 0; ni < 4; ++ni)
    bv[ni] = *(const float4*)&bias[fbase + ni * 16 + quad * 4];
  const int bh = m0 >> 11;          // in*2+b
  const int lbase = (m0 & 2047) + wm;

  if (s == 2) {
    u16* dst = vtb + (size_t)((bh * 8 + h) * 64) * 2048;
#pragma unroll
    for (int mi = 0; mi < 4; ++mi) {
      int l = lbase + mi * 16 + l16;
#pragma unroll
      for (int ni = 0; ni < 4; ++ni)
#pragma unroll
        for (int r = 0; r < 4; ++r)
          dst[(ni * 16 + quad * 4 + r) * 2048 + l] = f2bf(acc[mi][ni][r] + bv[ni][r]);
    }
  } else {
    u16* dst = (s == 0 ? qb : kb) + (size_t)((bh * 8 + h) * 2048) * 64;
    const float sc2 = (s == 0) ? 0.18033688011112042f : 1.0f;
#pragma unroll
    for (int mi = 0; mi < 4; ++mi) {
      int l = lbase + mi * 16 + l16;
#pragma unroll
      for (int ni = 0; ni < 4; ++ni) {
        float v0 = (acc[mi][ni][0] + bv[ni][0]) * sc2;
        float v1 = (acc[mi][ni][1] + bv[ni][1]) * sc2;
        float v2 = (acc[mi][ni][2] + bv[ni][2]) * sc2;
        float v3 = (acc[mi][ni][3] + bv[ni][3]) * sc2;
        *(uint2*)&dst[(size_t)l * 64 + ni * 16 + quad * 4] = make_uint2(pk2(v0, v1), pk2(v2, v3));
      }
    }
  }
}

// ---------------- kernel 2: flash cross-attention (S^T formulation) ----------------
// grid 512: 128 q-rows/block, 4 waves x 32 q-rows; K-tiles of 64.
// LDS 38912 B -> 4 blocks/CU; launch_bounds(256,4) permits 16 waves/CU.
#define LQ 72
#define LP 80

__global__ __launch_bounds__(256, 4) void attn_kernel(
    const u16* __restrict__ qb, const u16* __restrict__ kb, const u16* __restrict__ vtb,
    u16* __restrict__ attnb) {
  __shared__ __align__(16) u16 Ks[64 * LQ];
  __shared__ __align__(16) u16 VTs[64 * LQ];
  __shared__ __align__(16) u16 Ps[128 * LP];

  const int t = threadIdx.x;
  const int w = t >> 6, lane = t & 63, l16 = lane & 15, quad = lane >> 4;
  const int bid = blockIdx.x;
  const int qt = bid & 15;
  const int comb = bid >> 4;
  const int h = comb & 7, bb = (comb >> 3) & 1, pair = comb >> 4;
  const int in_q = pair, in_kv = pair ^ 1;

  const u16* Qg = qb + (size_t)((in_q * 2 + bb) * 8 + h) * 2048 * 64;
  const u16* Kg = kb + (size_t)((in_kv * 2 + bb) * 8 + h) * 2048 * 64;
  const u16* Vg = vtb + (size_t)((in_kv * 2 + bb) * 8 + h) * 64 * 2048;

#pragma unroll
  for (int u = 0; u < 4; ++u) {
    int idx = u * 256 + t;
    int row = idx >> 3, seg = (idx & 7) * 8;
    *(uint4*)&Ps[row * LP + seg] = *(const uint4*)(Qg + (qt * 128 + row) * 64 + seg);
  }
  __syncthreads();
  bf16x8 qf[2][2];
#pragma unroll
  for (int mi = 0; mi < 2; ++mi)
#pragma unroll
    for (int ks = 0; ks < 2; ++ks)
      qf[mi][ks] = *(const bf16x8*)&Ps[(w * 32 + mi * 16 + l16) * LP + ks * 32 + quad * 8];

  f32x4 oacc[2][4];
  float rs[2] = {0.f, 0.f};
#pragma unroll
  for (int mi = 0; mi < 2; ++mi)
#pragma unroll
    for (int ni = 0; ni < 4; ++ni) oacc[mi][ni] = (f32x4){0.f, 0.f, 0.f, 0.f};

  u16* Pw = &Ps[w * 32 * LP];

  const int srow = t >> 3, sseg = (t & 7) * 8;
  uint4 rk0 = *(const uint4*)(Kg + srow * 64 + sseg);
  uint4 rk1 = *(const uint4*)(Kg + (srow + 32) * 64 + sseg);
  uint4 rv0 = *(const uint4*)(Vg + srow * 2048 + sseg);
  uint4 rv1 = *(const uint4*)(Vg + (srow + 32) * 2048 + sseg);

  for (int kt = 0; kt < 32; ++kt) {
    __syncthreads();
    *(uint4*)&Ks[srow * LQ + sseg] = rk0;
    *(uint4*)&Ks[(srow + 32) * LQ + sseg] = rk1;
    *(uint4*)&VTs[srow * LQ + sseg] = rv0;
    *(uint4*)&VTs[(srow + 32) * LQ + sseg] = rv1;
    __syncthreads();
    if (kt < 31) {
      int ko = (kt + 1) * 64;
      rk0 = *(const uint4*)(Kg + (ko + srow) * 64 + sseg);
      rk1 = *(const uint4*)(Kg + (ko + srow + 32) * 64 + sseg);
      rv0 = *(const uint4*)(Vg + srow * 2048 + ko + sseg);
      rv1 = *(const uint4*)(Vg + (srow + 32) * 2048 + ko + sseg);
    }

    f32x4 sacc[2][4];
#pragma unroll
    for (int mi = 0; mi < 2; ++mi)
#pragma unroll
      for (int ni = 0; ni < 4; ++ni) sacc[mi][ni] = (f32x4){0.f, 0.f, 0.f, 0.f};
#pragma unroll
    for (int ks = 0; ks < 2; ++ks) {
      bf16x8 kfr[4];
#pragma unroll
      for (int ni = 0; ni < 4; ++ni)
        kfr[ni] = *(const bf16x8*)&Ks[(ni * 16 + l16) * LQ + ks * 32 + quad * 8];
#pragma unroll
      for (int mi = 0; mi < 2; ++mi)
#pragma unroll
        for (int ni = 0; ni < 4; ++ni)
          sacc[mi][ni] = __builtin_amdgcn_mfma_f32_16x16x32_bf16(kfr[ni], qf[mi][ks], sacc[mi][ni], 0, 0, 0);
    }

#pragma unroll
    for (int mi = 0; mi < 2; ++mi)
#pragma unroll
      for (int ni = 0; ni < 4; ++ni) {
        float p0 = exp2f(sacc[mi][ni][0]);
        float p1 = exp2f(sacc[mi][ni][1]);
        float p2 = exp2f(sacc[mi][ni][2]);
        float p3 = exp2f(sacc[mi][ni][3]);
        rs[mi] += (p0 + p1) + (p2 + p3);
        *(uint2*)&Pw[(mi * 16 + l16) * LP + ni * 16 + quad * 4] = make_uint2(pk2(p0, p1), pk2(p2, p3));
      }

#pragma unroll
    for (int ks = 0; ks < 2; ++ks) {
      bf16x8 vf[4], pf[2];
#pragma unroll
      for (int ni = 0; ni < 4; ++ni)
        vf[ni] = *(const bf16x8*)&VTs[(ni * 16 + l16) * LQ + ks * 32 + quad * 8];
#pragma unroll
      for (int mi = 0; mi < 2; ++mi)
        pf[mi] = *(const bf16x8*)&Pw[(mi * 16 + l16) * LP + ks * 32 + quad * 8];
#pragma unroll
      for (int mi = 0; mi < 2; ++mi)
#pragma unroll
        for (int ni = 0; ni < 4; ++ni)
          oacc[mi][ni] = __builtin_amdgcn_mfma_f32_16x16x32_bf16(vf[ni], pf[mi], oacc[mi][ni], 0, 0, 0);
    }
  }

  float inv[2];
#pragma unroll
  for (int mi = 0; mi < 2; ++mi) {
    float s = rs[mi];
    s += __shfl_xor(s, 16);
    s += __shfl_xor(s, 32);
    inv[mi] = 1.0f / s;
  }
  const int mbase = in_q * 4096 + bb * 2048 + qt * 128 + w * 32;
#pragma unroll
  for (int mi = 0; mi < 2; ++mi) {
    int row = mbase + mi * 16 + l16;
#pragma unroll
    for (int ni = 0; ni < 4; ++ni) {
      float v0 = oacc[mi][ni][0] * inv[mi];
      float v1 = oacc[mi][ni][1] * inv[mi];
      float v2 = oacc[mi][ni][2] * inv[mi];
      float v3 = oacc[mi][ni][3] * inv[mi];
      *(uint2*)&attnb[(size_t)row * 512 + h * 64 + ni * 16 + quad * 4] =
          make_uint2(pk2(v0, v1), pk2(v2, v3));
    }
  }
}

// ---------------- kernel 3: output projection (64x128 tiles, W fused-converted) ----------------
__global__ __launch_bounds__(256, 4) void out_gemm(
    const u16* __restrict__ A, const float* __restrict__ W, const float* __restrict__ bias,
    float* __restrict__ out) {
  __shared__ __align__(16) u16 As[64 * LDA];
  __shared__ __align__(16) u16 Bs[128 * LDA];
  const int t = threadIdx.x;
  const int m0 = blockIdx.x * 64, n0 = blockIdx.y * 128;
  const int lane = t & 63, l16 = lane & 15, quad = lane >> 4;
  const int w = t >> 6;
  const int wm = (w & 1) * 32, wn = (w >> 1) * 64;

  const int ar = t >> 2, ac = (t & 3) * 8;
  const u16* Ap = A + (size_t)(m0 + ar) * K_DIM + ac;
  const int wr = t >> 1, wc0 = (t & 1) * 16;
  const float* Wpf = W + (size_t)(n0 + wr) * K_DIM + wc0;

  f32x4 acc[2][4];
#pragma unroll
  for (int i = 0; i < 2; ++i)
#pragma unroll
    for (int j = 0; j < 4; ++j) acc[i][j] = (f32x4){0.f, 0.f, 0.f, 0.f};

  uint4 ra = *(const uint4*)Ap;
  float4 w4[4];
#pragma unroll
  for (int j = 0; j < 4; ++j) w4[j] = ((const float4*)Wpf)[j];

  for (int kt = 0; kt < 16; ++kt) {
    *(uint4*)&As[ar * LDA + ac] = ra;
    *(uint4*)&Bs[wr * LDA + wc0]     = pk8(w4[0], w4[1]);
    *(uint4*)&Bs[wr * LDA + wc0 + 8] = pk8(w4[2], w4[3]);
    __syncthreads();
    if (kt < 15) {
      int ko = (kt + 1) * 32;
      ra = *(const uint4*)(Ap + ko);
#pragma unroll
      for (int j = 0; j < 4; ++j) w4[j] = ((const float4*)(Wpf + ko))[j];
    }
    bf16x8 af[2], bfr[4];
#pragma unroll
    for (int mi = 0; mi < 2; ++mi)
      af[mi] = *(const bf16x8*)&As[(wm + mi * 16 + l16) * LDA + quad * 8];
#pragma unroll
    for (int ni = 0; ni < 4; ++ni)
      bfr[ni] = *(const bf16x8*)&Bs[(wn + ni * 16 + l16) * LDA + quad * 8];
#pragma unroll
    for (int mi = 0; mi < 2; ++mi)
#pragma unroll
      for (int ni = 0; ni < 4; ++ni)
        acc[mi][ni] = __builtin_amdgcn_mfma_f32_16x16x32_bf16(af[mi], bfr[ni], acc[mi][ni], 0, 0, 0);
    __syncthreads();
  }

#pragma unroll
  for (int ni = 0; ni < 4; ++ni) {
    int f = n0 + wn + ni * 16 + l16;
    float bv = bias[f];
#pragma unroll
    for (int mi = 0; mi < 2; ++mi)
#pragma unroll
      for (int r = 0; r < 4; ++r) {
        int m = m0 + wm + mi * 16 + quad * 4 + r;
        out[(size_t)m * 512 + f] = acc[mi][ni][r] + bv;
      }
  }
}

// ---------------- launcher ----------------
extern "C" void kernel_launch(void* const* d_in, const int* in_sizes, int n_in,
                              void* d_out, int out_size, void* d_ws, size_t ws_size,
                              hipStream_t stream) {
  const float* x1   = (const float*)d_in[0];
  const float* x2   = (const float*)d_in[1];
  const float* qkvw = (const float*)d_in[2];
  const float* qkvb = (const float*)d_in[3];
  const float* outw = (const float*)d_in[4];
  const float* outb = (const float*)d_in[5];
  float* out = (float*)d_out;
  char* ws = (char*)d_ws;

  u16* qb    = (u16*)(ws + 0);          // [2][2][8][2048][64]
  u16* kb    = (u16*)(ws + 8388608);    // [2][2][8][2048][64]
  u16* vtb   = (u16*)(ws + 16777216);   // [2][2][8][64][2048]
  u16* attnb = (u16*)(ws + 25165824);   // [8192][512]

  dim3 g1(64, 12);
  qkv_gemm<<<g1, 256, 0, stream>>>(x1, x2, qkvw, qkvb, qb, kb, vtb);

  attn_kernel<<<512, 256, 0, stream>>>(qb, kb, vtb, attnb);

  dim3 g3(128, 4);
  out_gemm<<<g3, 256, 0, stream>>>(attnb, outw, outb, out);
}

// Round 7
// 175.539 us; speedup vs baseline: 1.1044x; 1.1044x over previous
//
#include <hip/hip_runtime.h>
#include <stdint.h>

typedef unsigned short u16;
typedef unsigned int u32;
typedef short bf16x8 __attribute__((ext_vector_type(8)));
typedef float f32x4 __attribute__((ext_vector_type(4)));

#define K_DIM 512

__device__ __forceinline__ u16 f2bf(float f) {
  union { float f; u32 u; } v; v.f = f;
  return (u16)((v.u + 0x8000u) >> 16);  // round-half-up
}
__device__ __forceinline__ u32 pk2(float lo, float hi) {
  union { float f; u32 u; } a, b; a.f = lo; b.f = hi;
  return __builtin_amdgcn_perm(b.u + 0x8000u, a.u + 0x8000u, 0x07060302u);
}

// ---------------- kernel 0: fp32 -> bf16 conversions ----------------
// float4 counts: x1 524288, x2 524288, qkv_w 196608, out_w 65536 -> 5120 blocks.
__global__ void cvt_kernel(const float* __restrict__ x1, const float* __restrict__ x2,
                           const float* __restrict__ qkvw, const float* __restrict__ outw,
                           u16* __restrict__ xb, u16* __restrict__ wqkv, u16* __restrict__ wout) {
  int tid = blockIdx.x * 256 + threadIdx.x;
  const float4* src; u16* dst; int idx = tid;
  if (idx < 524288)        { src = (const float4*)x1;   dst = xb; }
  else if (idx < 1048576)  { src = (const float4*)x2;   dst = xb + 2097152; idx -= 524288; }
  else if (idx < 1245184)  { src = (const float4*)qkvw; dst = wqkv;         idx -= 1048576; }
  else                     { src = (const float4*)outw; dst = wout;         idx -= 1245184; }
  float4 v = src[idx];
  *(uint2*)&dst[idx * 4] = make_uint2(pk2(v.x, v.y), pk2(v.z, v.w));
}

#define LDA 40  // BK=32 + 8 pad

// ---------------- kernel 1: QKV GEMM (C^T, dbuf single-barrier) + scatter epilogue ----------------
// f = h*192 + s*64 + d. q scaled by (1/8)*log2(e); q/k layout [in,b,h,l,d]; v transposed [in,b,h,d,l].
__global__ __launch_bounds__(256, 3) void qkv_gemm(
    const u16* __restrict__ A, const u16* __restrict__ W, const float* __restrict__ bias,
    u16* __restrict__ qb, u16* __restrict__ kb, u16* __restrict__ vtb) {
  __shared__ __align__(16) u16 As[2][128 * LDA];
  __shared__ __align__(16) u16 Bs[2][128 * LDA];
  const int t = threadIdx.x;
  const int m0 = blockIdx.x * 128, n0 = blockIdx.y * 128;
  const int lane = t & 63, l16 = lane & 15, quad = lane >> 4;
  const int w = t >> 6;
  const int wm = (w >> 1) * 64, wn = (w & 1) * 64;
  const int sr = t >> 2, sc = (t & 3) * 8;

  const u16* Ap = A + (size_t)(m0 + sr) * K_DIM + sc;
  const u16* Wp = W + (size_t)(n0 + sr) * K_DIM + sc;

  f32x4 acc[4][4];
#pragma unroll
  for (int i = 0; i < 4; ++i)
#pragma unroll
    for (int j = 0; j < 4; ++j) acc[i][j] = (f32x4){0.f, 0.f, 0.f, 0.f};

  // prologue: tile0 -> buf0; tile1 -> regs
  uint4 ra0 = *(const uint4*)(Ap);
  uint4 ra1 = *(const uint4*)(Ap + 64 * K_DIM);
  uint4 rb0 = *(const uint4*)(Wp);
  uint4 rb1 = *(const uint4*)(Wp + 64 * K_DIM);
  *(uint4*)&As[0][sr * LDA + sc] = ra0;
  *(uint4*)&As[0][(sr + 64) * LDA + sc] = ra1;
  *(uint4*)&Bs[0][sr * LDA + sc] = rb0;
  *(uint4*)&Bs[0][(sr + 64) * LDA + sc] = rb1;
  ra0 = *(const uint4*)(Ap + 32);
  ra1 = *(const uint4*)(Ap + 64 * K_DIM + 32);
  rb0 = *(const uint4*)(Wp + 32);
  rb1 = *(const uint4*)(Wp + 64 * K_DIM + 32);
  __syncthreads();

  for (int kt = 0; kt < 16; ++kt) {
    const int cur = kt & 1, nxt = cur ^ 1;
    if (kt < 15) {
      *(uint4*)&As[nxt][sr * LDA + sc] = ra0;
      *(uint4*)&As[nxt][(sr + 64) * LDA + sc] = ra1;
      *(uint4*)&Bs[nxt][sr * LDA + sc] = rb0;
      *(uint4*)&Bs[nxt][(sr + 64) * LDA + sc] = rb1;
    }
    if (kt < 14) {
      int ko = (kt + 2) * 32;
      ra0 = *(const uint4*)(Ap + ko);
      ra1 = *(const uint4*)(Ap + 64 * K_DIM + ko);
      rb0 = *(const uint4*)(Wp + ko);
      rb1 = *(const uint4*)(Wp + 64 * K_DIM + ko);
    }
    bf16x8 af[4], bfr[4];
#pragma unroll
    for (int mi = 0; mi < 4; ++mi)
      af[mi] = *(const bf16x8*)&As[cur][(wm + mi * 16 + l16) * LDA + quad * 8];
#pragma unroll
    for (int ni = 0; ni < 4; ++ni)
      bfr[ni] = *(const bf16x8*)&Bs[cur][(wn + ni * 16 + l16) * LDA + quad * 8];
    // SWAPPED operands: C^T -> row(quad,r)=f-offset, col(l16)=m-offset
#pragma unroll
    for (int mi = 0; mi < 4; ++mi)
#pragma unroll
      for (int ni = 0; ni < 4; ++ni)
        acc[mi][ni] = __builtin_amdgcn_mfma_f32_16x16x32_bf16(bfr[ni], af[mi], acc[mi][ni], 0, 0, 0);
    __syncthreads();
  }

  const int fbase = n0 + wn;                 // 64-aligned
  const int h = fbase / 192;
  const int s = (fbase - h * 192) >> 6;      // wave-uniform
  float4 bv[4];
#pragma unroll
  for (int ni = 0; ni < 4; ++ni)
    bv[ni] = *(const float4*)&bias[fbase + ni * 16 + quad * 4];
  const int bh = m0 >> 11;                   // in*2+b
  const int lbase = (m0 & 2047) + wm;

  if (s == 2) {
    u16* dst = vtb + (size_t)((bh * 8 + h) * 64) * 2048;
#pragma unroll
    for (int mi = 0; mi < 4; ++mi) {
      int l = lbase + mi * 16 + l16;
#pragma unroll
      for (int ni = 0; ni < 4; ++ni)
#pragma unroll
        for (int r = 0; r < 4; ++r)
          dst[(ni * 16 + quad * 4 + r) * 2048 + l] = f2bf(acc[mi][ni][r] + bv[ni][r]);
    }
  } else {
    u16* dst = (s == 0 ? qb : kb) + (size_t)((bh * 8 + h) * 2048) * 64;
    const float sc2 = (s == 0) ? 0.18033688011112042f : 1.0f;
#pragma unroll
    for (int mi = 0; mi < 4; ++mi) {
      int l = lbase + mi * 16 + l16;
#pragma unroll
      for (int ni = 0; ni < 4; ++ni) {
        float v0 = (acc[mi][ni][0] + bv[ni][0]) * sc2;
        float v1 = (acc[mi][ni][1] + bv[ni][1]) * sc2;
        float v2 = (acc[mi][ni][2] + bv[ni][2]) * sc2;
        float v3 = (acc[mi][ni][3] + bv[ni][3]) * sc2;
        *(uint2*)&dst[(size_t)l * 64 + ni * 16 + quad * 4] = make_uint2(pk2(v0, v1), pk2(v2, v3));
      }
    }
  }
}

// ---------------- kernel 2: flash cross-attention (S^T, dbuf K/V, 1 barrier/iter) ----------------
// grid 512: 128 q-rows/block, 4 waves x 32 q-rows; K-tiles of 64.
// LDS: 2*(Ks 9216 + VTs 9216) + Ps 20480 = 57344 B -> 2 blocks/CU.
#define LQ 72
#define LP 80

__global__ __launch_bounds__(256, 2) void attn_kernel(
    const u16* __restrict__ qb, const u16* __restrict__ kb, const u16* __restrict__ vtb,
    u16* __restrict__ attnb) {
  __shared__ __align__(16) u16 Ks[2][64 * LQ];
  __shared__ __align__(16) u16 VTs[2][64 * LQ];
  __shared__ __align__(16) u16 Ps[128 * LP];   // Q staging, then per-wave P buffers

  const int t = threadIdx.x;
  const int w = t >> 6, lane = t & 63, l16 = lane & 15, quad = lane >> 4;
  const int bid = blockIdx.x;
  const int qt = bid & 15;
  const int comb = bid >> 4;
  const int h = comb & 7, bb = (comb >> 3) & 1, pair = comb >> 4;
  const int in_q = pair, in_kv = pair ^ 1;

  const u16* Qg = qb + (size_t)((in_q * 2 + bb) * 8 + h) * 2048 * 64;
  const u16* Kg = kb + (size_t)((in_kv * 2 + bb) * 8 + h) * 2048 * 64;
  const u16* Vg = vtb + (size_t)((in_kv * 2 + bb) * 8 + h) * 64 * 2048;

  // stage Q [128][64] into Ps (stride LP)
#pragma unroll
  for (int u = 0; u < 4; ++u) {
    int idx = u * 256 + t;
    int row = idx >> 3, seg = (idx & 7) * 8;
    *(uint4*)&Ps[row * LP + seg] = *(const uint4*)(Qg + (qt * 128 + row) * 64 + seg);
  }

  // prologue: K/V tile0 -> buf0; tile1 -> regs
  const int srow = t >> 3, sseg = (t & 7) * 8;
  uint4 rk0 = *(const uint4*)(Kg + srow * 64 + sseg);
  uint4 rk1 = *(const uint4*)(Kg + (srow + 32) * 64 + sseg);
  uint4 rv0 = *(const uint4*)(Vg + srow * 2048 + sseg);
  uint4 rv1 = *(const uint4*)(Vg + (srow + 32) * 2048 + sseg);
  *(uint4*)&Ks[0][srow * LQ + sseg] = rk0;
  *(uint4*)&Ks[0][(srow + 32) * LQ + sseg] = rk1;
  *(uint4*)&VTs[0][srow * LQ + sseg] = rv0;
  *(uint4*)&VTs[0][(srow + 32) * LQ + sseg] = rv1;
  rk0 = *(const uint4*)(Kg + (64 + srow) * 64 + sseg);
  rk1 = *(const uint4*)(Kg + (64 + srow + 32) * 64 + sseg);
  rv0 = *(const uint4*)(Vg + srow * 2048 + 64 + sseg);
  rv1 = *(const uint4*)(Vg + (srow + 32) * 2048 + 64 + sseg);
  __syncthreads();   // Q + buf0 visible

  bf16x8 qf[2][2];
#pragma unroll
  for (int mi = 0; mi < 2; ++mi)
#pragma unroll
    for (int ks = 0; ks < 2; ++ks)
      qf[mi][ks] = *(const bf16x8*)&Ps[(w * 32 + mi * 16 + l16) * LP + ks * 32 + quad * 8];

  f32x4 oacc[2][4];
  float rs[2] = {0.f, 0.f};
#pragma unroll
  for (int mi = 0; mi < 2; ++mi)
#pragma unroll
    for (int ni = 0; ni < 4; ++ni) oacc[mi][ni] = (f32x4){0.f, 0.f, 0.f, 0.f};

  u16* Pw = &Ps[w * 32 * LP];   // wave-private (aliases this wave's own Q rows; qf hoisted)

  for (int kt = 0; kt < 32; ++kt) {
    const int cur = kt & 1, nxt = cur ^ 1;
    if (kt < 31) {
      *(uint4*)&Ks[nxt][srow * LQ + sseg] = rk0;
      *(uint4*)&Ks[nxt][(srow + 32) * LQ + sseg] = rk1;
      *(uint4*)&VTs[nxt][srow * LQ + sseg] = rv0;
      *(uint4*)&VTs[nxt][(srow + 32) * LQ + sseg] = rv1;
    }
    if (kt < 30) {
      int ko = (kt + 2) * 64;
      rk0 = *(const uint4*)(Kg + (ko + srow) * 64 + sseg);
      rk1 = *(const uint4*)(Kg + (ko + srow + 32) * 64 + sseg);
      rv0 = *(const uint4*)(Vg + srow * 2048 + ko + sseg);
      rv1 = *(const uint4*)(Vg + (srow + 32) * 2048 + ko + sseg);
    }

    // S^T[kcol][qrow] = mfma(K-frag, Q-frag)
    f32x4 sacc[2][4];
#pragma unroll
    for (int mi = 0; mi < 2; ++mi)
#pragma unroll
      for (int ni = 0; ni < 4; ++ni) sacc[mi][ni] = (f32x4){0.f, 0.f, 0.f, 0.f};
#pragma unroll
    for (int ks = 0; ks < 2; ++ks) {
      bf16x8 kfr[4];
#pragma unroll
      for (int ni = 0; ni < 4; ++ni)
        kfr[ni] = *(const bf16x8*)&Ks[cur][(ni * 16 + l16) * LQ + ks * 32 + quad * 8];
#pragma unroll
      for (int mi = 0; mi < 2; ++mi)
#pragma unroll
        for (int ni = 0; ni < 4; ++ni)
          sacc[mi][ni] = __builtin_amdgcn_mfma_f32_16x16x32_bf16(kfr[ni], qf[mi][ks], sacc[mi][ni], 0, 0, 0);
    }

    // p = exp2(s); lane's 4 r-values = 4 consecutive kcols of qrow (mi,l16) -> b64 write
#pragma unroll
    for (int mi = 0; mi < 2; ++mi)
#pragma unroll
      for (int ni = 0; ni < 4; ++ni) {
        float p0 = exp2f(sacc[mi][ni][0]);
        float p1 = exp2f(sacc[mi][ni][1]);
        float p2 = exp2f(sacc[mi][ni][2]);
        float p3 = exp2f(sacc[mi][ni][3]);
        rs[mi] += (p0 + p1) + (p2 + p3);
        *(uint2*)&Pw[(mi * 16 + l16) * LP + ni * 16 + quad * 4] = make_uint2(pk2(p0, p1), pk2(p2, p3));
      }

    // O^T[d][qrow] += mfma(V^T-frag, P-frag)
#pragma unroll
    for (int ks = 0; ks < 2; ++ks) {
      bf16x8 vf[4], pf[2];
#pragma unroll
      for (int ni = 0; ni < 4; ++ni)
        vf[ni] = *(const bf16x8*)&VTs[cur][(ni * 16 + l16) * LQ + ks * 32 + quad * 8];
#pragma unroll
      for (int mi = 0; mi < 2; ++mi)
        pf[mi] = *(const bf16x8*)&Pw[(mi * 16 + l16) * LP + ks * 32 + quad * 8];
#pragma unroll
      for (int mi = 0; mi < 2; ++mi)
#pragma unroll
        for (int ni = 0; ni < 4; ++ni)
          oacc[mi][ni] = __builtin_amdgcn_mfma_f32_16x16x32_bf16(vf[ni], pf[mi], oacc[mi][ni], 0, 0, 0);
    }
    __syncthreads();   // single barrier per iter: protects next iter's buf write
  }

  // epilogue: reduce row-sums across quads (rows keyed by (mi,l16)), write O^T normalized
  float inv[2];
#pragma unroll
  for (int mi = 0; mi < 2; ++mi) {
    float s = rs[mi];
    s += __shfl_xor(s, 16);
    s += __shfl_xor(s, 32);
    inv[mi] = 1.0f / s;
  }
  const int mbase = in_q * 4096 + bb * 2048 + qt * 128 + w * 32;
#pragma unroll
  for (int mi = 0; mi < 2; ++mi) {
    int row = mbase + mi * 16 + l16;
#pragma unroll
    for (int ni = 0; ni < 4; ++ni) {
      float v0 = oacc[mi][ni][0] * inv[mi];
      float v1 = oacc[mi][ni][1] * inv[mi];
      float v2 = oacc[mi][ni][2] * inv[mi];
      float v3 = oacc[mi][ni][3] * inv[mi];
      *(uint2*)&attnb[(size_t)row * 512 + h * 64 + ni * 16 + quad * 4] =
          make_uint2(pk2(v0, v1), pk2(v2, v3));
    }
  }
}

// ---------------- kernel 3: output projection (64x128 tiles, dbuf) ----------------
__global__ __launch_bounds__(256, 2) void out_gemm(
    const u16* __restrict__ A, const u16* __restrict__ W, const float* __restrict__ bias,
    float* __restrict__ out) {
  __shared__ __align__(16) u16 As[2][64 * LDA];
  __shared__ __align__(16) u16 Bs[2][128 * LDA];
  const int t = threadIdx.x;
  const int m0 = blockIdx.x * 64, n0 = blockIdx.y * 128;
  const int lane = t & 63, l16 = lane & 15, quad = lane >> 4;
  const int w = t >> 6;
  const int wm = (w & 1) * 32, wn = (w >> 1) * 64;
  const int ar = t >> 2, ac = (t & 3) * 8;      // A: 64 rows x 32 cols, 4 thr/row
  const int sr = t >> 2, sc = (t & 3) * 8;      // B: 128 rows via two stores

  const u16* Ap = A + (size_t)(m0 + ar) * K_DIM + ac;
  const u16* Wp = W + (size_t)(n0 + sr) * K_DIM + sc;

  f32x4 acc[2][4];
#pragma unroll
  for (int i = 0; i < 2; ++i)
#pragma unroll
    for (int j = 0; j < 4; ++j) acc[i][j] = (f32x4){0.f, 0.f, 0.f, 0.f};

  uint4 ra = *(const uint4*)Ap;
  uint4 rb0 = *(const uint4*)(Wp);
  uint4 rb1 = *(const uint4*)(Wp + 64 * K_DIM);
  *(uint4*)&As[0][ar * LDA + ac] = ra;
  *(uint4*)&Bs[0][sr * LDA + sc] = rb0;
  *(uint4*)&Bs[0][(sr + 64) * LDA + sc] = rb1;
  ra = *(const uint4*)(Ap + 32);
  rb0 = *(const uint4*)(Wp + 32);
  rb1 = *(const uint4*)(Wp + 64 * K_DIM + 32);
  __syncthreads();

  for (int kt = 0; kt < 16; ++kt) {
    const int cur = kt & 1, nxt = cur ^ 1;
    if (kt < 15) {
      *(uint4*)&As[nxt][ar * LDA + ac] = ra;
      *(uint4*)&Bs[nxt][sr * LDA + sc] = rb0;
      *(uint4*)&Bs[nxt][(sr + 64) * LDA + sc] = rb1;
    }
    if (kt < 14) {
      int ko = (kt + 2) * 32;
      ra = *(const uint4*)(Ap + ko);
      rb0 = *(const uint4*)(Wp + ko);
      rb1 = *(const uint4*)(Wp + 64 * K_DIM + ko);
    }
    bf16x8 af[2], bfr[4];
#pragma unroll
    for (int mi = 0; mi < 2; ++mi)
      af[mi] = *(const bf16x8*)&As[cur][(wm + mi * 16 + l16) * LDA + quad * 8];
#pragma unroll
    for (int ni = 0; ni < 4; ++ni)
      bfr[ni] = *(const bf16x8*)&Bs[cur][(wn + ni * 16 + l16) * LDA + quad * 8];
#pragma unroll
    for (int mi = 0; mi < 2; ++mi)
#pragma unroll
      for (int ni = 0; ni < 4; ++ni)
        acc[mi][ni] = __builtin_amdgcn_mfma_f32_16x16x32_bf16(af[mi], bfr[ni], acc[mi][ni], 0, 0, 0);
    __syncthreads();
  }

#pragma unroll
  for (int ni = 0; ni < 4; ++ni) {
    int f = n0 + wn + ni * 16 + l16;
    float bv = bias[f];
#pragma unroll
    for (int mi = 0; mi < 2; ++mi)
#pragma unroll
      for (int r = 0; r < 4; ++r) {
        int m = m0 + wm + mi * 16 + quad * 4 + r;
        out[(size_t)m * 512 + f] = acc[mi][ni][r] + bv;
      }
  }
}

// ---------------- launcher ----------------
extern "C" void kernel_launch(void* const* d_in, const int* in_sizes, int n_in,
                              void* d_out, int out_size, void* d_ws, size_t ws_size,
                              hipStream_t stream) {
  const float* x1   = (const float*)d_in[0];
  const float* x2   = (const float*)d_in[1];
  const float* qkvw = (const float*)d_in[2];
  const float* qkvb = (const float*)d_in[3];
  const float* outw = (const float*)d_in[4];
  const float* outb = (const float*)d_in[5];
  float* out = (float*)d_out;
  char* ws = (char*)d_ws;

  // workspace (bytes), total 34 MiB. attnb ALIASES xb (xb dead after qkv_gemm).
  u16* xb    = (u16*)(ws + 0);          // [8192][512] bf16 (x1 rows 0..4095, x2 rows 4096..8191)
  u16* wqkv  = (u16*)(ws + 8388608);    // [1536][512]
  u16* wout  = (u16*)(ws + 9961472);    // [512][512]
  u16* qb    = (u16*)(ws + 10485760);   // [2][2][8][2048][64]
  u16* kb    = (u16*)(ws + 18874368);   // [2][2][8][2048][64]
  u16* vtb   = (u16*)(ws + 27262976);   // [2][2][8][64][2048]
  u16* attnb = (u16*)(ws + 0);          // [8192][512]  (aliases xb)

  cvt_kernel<<<5120, 256, 0, stream>>>(x1, x2, qkvw, outw, xb, wqkv, wout);

  dim3 g1(64, 12);
  qkv_gemm<<<g1, 256, 0, stream>>>(xb, wqkv, qkvb, qb, kb, vtb);

  attn_kernel<<<512, 256, 0, stream>>>(qb, kb, vtb, attnb);

  dim3 g3(128, 4);
  out_gemm<<<g3, 256, 0, stream>>>(attnb, wout, outb, out);
}

// Round 8
// 164.377 us; speedup vs baseline: 1.1794x; 1.0679x over previous
//
#include <hip/hip_runtime.h>
#include <stdint.h>

typedef unsigned short u16;
typedef unsigned int u32;
typedef short bf16x8 __attribute__((ext_vector_type(8)));
typedef float f32x4 __attribute__((ext_vector_type(4)));

#define K_DIM 512

__device__ __forceinline__ u16 f2bf(float f) {
  union { float f; u32 u; } v; v.f = f;
  return (u16)((v.u + 0x8000u) >> 16);  // round-half-up
}
__device__ __forceinline__ u32 pk2(float lo, float hi) {
  union { float f; u32 u; } a, b; a.f = lo; b.f = hi;
  return __builtin_amdgcn_perm(b.u + 0x8000u, a.u + 0x8000u, 0x07060302u);
}

// ---------------- kernel 0: fp32 -> bf16 conversions ----------------
__global__ void cvt_kernel(const float* __restrict__ x1, const float* __restrict__ x2,
                           const float* __restrict__ qkvw, const float* __restrict__ outw,
                           u16* __restrict__ xb, u16* __restrict__ wqkv, u16* __restrict__ wout) {
  int tid = blockIdx.x * 256 + threadIdx.x;
  const float4* src; u16* dst; int idx = tid;
  if (idx < 524288)        { src = (const float4*)x1;   dst = xb; }
  else if (idx < 1048576)  { src = (const float4*)x2;   dst = xb + 2097152; idx -= 524288; }
  else if (idx < 1245184)  { src = (const float4*)qkvw; dst = wqkv;         idx -= 1048576; }
  else                     { src = (const float4*)outw; dst = wout;         idx -= 1245184; }
  float4 v = src[idx];
  *(uint2*)&dst[idx * 4] = make_uint2(pk2(v.x, v.y), pk2(v.z, v.w));
}

#define LDA 40  // BK=32 + 8 pad

// ---------------- kernel 1: QKV GEMM (C^T, dbuf single-barrier) + scatter epilogue ----------------
__global__ __launch_bounds__(256, 3) void qkv_gemm(
    const u16* __restrict__ A, const u16* __restrict__ W, const float* __restrict__ bias,
    u16* __restrict__ qb, u16* __restrict__ kb, u16* __restrict__ vtb) {
  __shared__ __align__(16) u16 As[2][128 * LDA];
  __shared__ __align__(16) u16 Bs[2][128 * LDA];
  const int t = threadIdx.x;
  const int m0 = blockIdx.x * 128, n0 = blockIdx.y * 128;
  const int lane = t & 63, l16 = lane & 15, quad = lane >> 4;
  const int w = t >> 6;
  const int wm = (w >> 1) * 64, wn = (w & 1) * 64;
  const int sr = t >> 2, sc = (t & 3) * 8;

  const u16* Ap = A + (size_t)(m0 + sr) * K_DIM + sc;
  const u16* Wp = W + (size_t)(n0 + sr) * K_DIM + sc;

  f32x4 acc[4][4];
#pragma unroll
  for (int i = 0; i < 4; ++i)
#pragma unroll
    for (int j = 0; j < 4; ++j) acc[i][j] = (f32x4){0.f, 0.f, 0.f, 0.f};

  uint4 ra0 = *(const uint4*)(Ap);
  uint4 ra1 = *(const uint4*)(Ap + 64 * K_DIM);
  uint4 rb0 = *(const uint4*)(Wp);
  uint4 rb1 = *(const uint4*)(Wp + 64 * K_DIM);
  *(uint4*)&As[0][sr * LDA + sc] = ra0;
  *(uint4*)&As[0][(sr + 64) * LDA + sc] = ra1;
  *(uint4*)&Bs[0][sr * LDA + sc] = rb0;
  *(uint4*)&Bs[0][(sr + 64) * LDA + sc] = rb1;
  ra0 = *(const uint4*)(Ap + 32);
  ra1 = *(const uint4*)(Ap + 64 * K_DIM + 32);
  rb0 = *(const uint4*)(Wp + 32);
  rb1 = *(const uint4*)(Wp + 64 * K_DIM + 32);
  __syncthreads();

  for (int kt = 0; kt < 16; ++kt) {
    const int cur = kt & 1, nxt = cur ^ 1;
    if (kt < 15) {
      *(uint4*)&As[nxt][sr * LDA + sc] = ra0;
      *(uint4*)&As[nxt][(sr + 64) * LDA + sc] = ra1;
      *(uint4*)&Bs[nxt][sr * LDA + sc] = rb0;
      *(uint4*)&Bs[nxt][(sr + 64) * LDA + sc] = rb1;
    }
    if (kt < 14) {
      int ko = (kt + 2) * 32;
      ra0 = *(const uint4*)(Ap + ko);
      ra1 = *(const uint4*)(Ap + 64 * K_DIM + ko);
      rb0 = *(const uint4*)(Wp + ko);
      rb1 = *(const uint4*)(Wp + 64 * K_DIM + ko);
    }
    bf16x8 af[4], bfr[4];
#pragma unroll
    for (int mi = 0; mi < 4; ++mi)
      af[mi] = *(const bf16x8*)&As[cur][(wm + mi * 16 + l16) * LDA + quad * 8];
#pragma unroll
    for (int ni = 0; ni < 4; ++ni)
      bfr[ni] = *(const bf16x8*)&Bs[cur][(wn + ni * 16 + l16) * LDA + quad * 8];
#pragma unroll
    for (int mi = 0; mi < 4; ++mi)
#pragma unroll
      for (int ni = 0; ni < 4; ++ni)
        acc[mi][ni] = __builtin_amdgcn_mfma_f32_16x16x32_bf16(bfr[ni], af[mi], acc[mi][ni], 0, 0, 0);
    __syncthreads();
  }

  const int fbase = n0 + wn;
  const int h = fbase / 192;
  const int s = (fbase - h * 192) >> 6;
  float4 bv[4];
#pragma unroll
  for (int ni = 0; ni < 4; ++ni)
    bv[ni] = *(const float4*)&bias[fbase + ni * 16 + quad * 4];
  const int bh = m0 >> 11;
  const int lbase = (m0 & 2047) + wm;

  if (s == 2) {
    u16* dst = vtb + (size_t)((bh * 8 + h) * 64) * 2048;
#pragma unroll
    for (int mi = 0; mi < 4; ++mi) {
      int l = lbase + mi * 16 + l16;
#pragma unroll
      for (int ni = 0; ni < 4; ++ni)
#pragma unroll
        for (int r = 0; r < 4; ++r)
          dst[(ni * 16 + quad * 4 + r) * 2048 + l] = f2bf(acc[mi][ni][r] + bv[ni][r]);
    }
  } else {
    u16* dst = (s == 0 ? qb : kb) + (size_t)((bh * 8 + h) * 2048) * 64;
    const float sc2 = (s == 0) ? 0.18033688011112042f : 1.0f;
#pragma unroll
    for (int mi = 0; mi < 4; ++mi) {
      int l = lbase + mi * 16 + l16;
#pragma unroll
      for (int ni = 0; ni < 4; ++ni) {
        float v0 = (acc[mi][ni][0] + bv[ni][0]) * sc2;
        float v1 = (acc[mi][ni][1] + bv[ni][1]) * sc2;
        float v2 = (acc[mi][ni][2] + bv[ni][2]) * sc2;
        float v3 = (acc[mi][ni][3] + bv[ni][3]) * sc2;
        *(uint2*)&dst[(size_t)l * 64 + ni * 16 + quad * 4] = make_uint2(pk2(v0, v1), pk2(v2, v3));
      }
    }
  }
}

// ---------------- kernel 2: flash cross-attention (S^T, 512-thread blocks) ----------------
// grid 512: 128 q-rows/block, 8 waves x 16 q-rows; K-tiles of 64; 2 blocks/CU = 16 waves/CU.
// LDS: Ks 64x72 (9216) + VTs 64x72 (9216) + Ps 128x72 (18432) = 36864 B.
#define LQ 72
#define LP 72

__global__ __launch_bounds__(512, 4) void attn_kernel(
    const u16* __restrict__ qb, const u16* __restrict__ kb, const u16* __restrict__ vtb,
    u16* __restrict__ attnb) {
  __shared__ __align__(16) u16 Ks[64 * LQ];
  __shared__ __align__(16) u16 VTs[64 * LQ];
  __shared__ __align__(16) u16 Ps[128 * LP];   // Q staging, then per-wave P buffers

  const int t = threadIdx.x;
  const int w = t >> 6, lane = t & 63, l16 = lane & 15, quad = lane >> 4;
  const int bid = blockIdx.x;
  const int qt = bid & 15;
  const int comb = bid >> 4;
  const int h = comb & 7, bb = (comb >> 3) & 1, pair = comb >> 4;
  const int in_q = pair, in_kv = pair ^ 1;

  const u16* Qg = qb + (size_t)((in_q * 2 + bb) * 8 + h) * 2048 * 64;
  const u16* Kg = kb + (size_t)((in_kv * 2 + bb) * 8 + h) * 2048 * 64;
  const u16* Vg = vtb + (size_t)((in_kv * 2 + bb) * 8 + h) * 64 * 2048;

  // stage Q [128][64] into Ps (stride LP): 1024 uint4, 2 per thread
#pragma unroll
  for (int u = 0; u < 2; ++u) {
    int idx = u * 512 + t;
    int row = idx >> 3, seg = (idx & 7) * 8;
    *(uint4*)&Ps[row * LP + seg] = *(const uint4*)(Qg + (qt * 128 + row) * 64 + seg);
  }
  // prefetch K/V tile 0: 1 uint4 each per thread
  const int srow = t >> 3, sseg = (t & 7) * 8;   // srow 0..63
  uint4 rk = *(const uint4*)(Kg + srow * 64 + sseg);
  uint4 rv = *(const uint4*)(Vg + srow * 2048 + sseg);
  __syncthreads();   // Q staged & visible

  // hoist Q frags (wave w owns q-rows w*16..+15; same rows later reused as its P buffer)
  bf16x8 qf[2];
#pragma unroll
  for (int ks = 0; ks < 2; ++ks)
    qf[ks] = *(const bf16x8*)&Ps[(w * 16 + l16) * LP + ks * 32 + quad * 8];

  f32x4 oacc[4];
  float rs = 0.f;
#pragma unroll
  for (int ni = 0; ni < 4; ++ni) oacc[ni] = (f32x4){0.f, 0.f, 0.f, 0.f};

  u16* Pw = &Ps[w * 16 * LP];   // wave-private P rows [16][LP]

  for (int kt = 0; kt < 32; ++kt) {
    // stage current tile (regs -> LDS); prev iter's readers finished at bottom barrier
    *(uint4*)&Ks[srow * LQ + sseg] = rk;
    *(uint4*)&VTs[srow * LQ + sseg] = rv;
    __syncthreads();
    if (kt < 31) {
      int ko = (kt + 1) * 64;
      rk = *(const uint4*)(Kg + (ko + srow) * 64 + sseg);
      rv = *(const uint4*)(Vg + srow * 2048 + ko + sseg);
    }

    // S^T[kcol][qrow] = mfma(K-frag, Q-frag)
    f32x4 sacc[4];
#pragma unroll
    for (int ni = 0; ni < 4; ++ni) sacc[ni] = (f32x4){0.f, 0.f, 0.f, 0.f};
#pragma unroll
    for (int ks = 0; ks < 2; ++ks) {
      bf16x8 kfr[4];
#pragma unroll
      for (int ni = 0; ni < 4; ++ni)
        kfr[ni] = *(const bf16x8*)&Ks[(ni * 16 + l16) * LQ + ks * 32 + quad * 8];
#pragma unroll
      for (int ni = 0; ni < 4; ++ni)
        sacc[ni] = __builtin_amdgcn_mfma_f32_16x16x32_bf16(kfr[ni], qf[ks], sacc[ni], 0, 0, 0);
    }

    // p = exp2(s) (native); lane's 4 r-values = 4 consecutive kcols of qrow l16 -> b64 write
#pragma unroll
    for (int ni = 0; ni < 4; ++ni) {
      float p0 = __builtin_amdgcn_exp2f(sacc[ni][0]);
      float p1 = __builtin_amdgcn_exp2f(sacc[ni][1]);
      float p2 = __builtin_amdgcn_exp2f(sacc[ni][2]);
      float p3 = __builtin_amdgcn_exp2f(sacc[ni][3]);
      rs += (p0 + p1) + (p2 + p3);
      *(uint2*)&Pw[l16 * LP + ni * 16 + quad * 4] = make_uint2(pk2(p0, p1), pk2(p2, p3));
    }

    // O^T[d][qrow] += mfma(V^T-frag, P-frag)
#pragma unroll
    for (int ks = 0; ks < 2; ++ks) {
      bf16x8 vf[4];
#pragma unroll
      for (int ni = 0; ni < 4; ++ni)
        vf[ni] = *(const bf16x8*)&VTs[(ni * 16 + l16) * LQ + ks * 32 + quad * 8];
      bf16x8 pf = *(const bf16x8*)&Pw[l16 * LP + ks * 32 + quad * 8];
#pragma unroll
      for (int ni = 0; ni < 4; ++ni)
        oacc[ni] = __builtin_amdgcn_mfma_f32_16x16x32_bf16(vf[ni], pf, oacc[ni], 0, 0, 0);
    }
    __syncthreads();   // all waves done reading Ks/VTs; next iter may overwrite
  }

  // epilogue: row-sum across quads (qrow keyed by l16), write O^T normalized
  float s = rs;
  s += __shfl_xor(s, 16);
  s += __shfl_xor(s, 32);
  const float inv = 1.0f / s;
  const int row = in_q * 4096 + bb * 2048 + qt * 128 + w * 16 + l16;
#pragma unroll
  for (int ni = 0; ni < 4; ++ni) {
    float v0 = oacc[ni][0] * inv;
    float v1 = oacc[ni][1] * inv;
    float v2 = oacc[ni][2] * inv;
    float v3 = oacc[ni][3] * inv;
    *(uint2*)&attnb[(size_t)row * 512 + h * 64 + ni * 16 + quad * 4] =
        make_uint2(pk2(v0, v1), pk2(v2, v3));
  }
}

// ---------------- kernel 3: output projection (64x128 tiles, dbuf) ----------------
__global__ __launch_bounds__(256, 2) void out_gemm(
    const u16* __restrict__ A, const u16* __restrict__ W, const float* __restrict__ bias,
    float* __restrict__ out) {
  __shared__ __align__(16) u16 As[2][64 * LDA];
  __shared__ __align__(16) u16 Bs[2][128 * LDA];
  const int t = threadIdx.x;
  const int m0 = blockIdx.x * 64, n0 = blockIdx.y * 128;
  const int lane = t & 63, l16 = lane & 15, quad = lane >> 4;
  const int w = t >> 6;
  const int wm = (w & 1) * 32, wn = (w >> 1) * 64;
  const int ar = t >> 2, ac = (t & 3) * 8;
  const int sr = t >> 2, sc = (t & 3) * 8;

  const u16* Ap = A + (size_t)(m0 + ar) * K_DIM + ac;
  const u16* Wp = W + (size_t)(n0 + sr) * K_DIM + sc;

  f32x4 acc[2][4];
#pragma unroll
  for (int i = 0; i < 2; ++i)
#pragma unroll
    for (int j = 0; j < 4; ++j) acc[i][j] = (f32x4){0.f, 0.f, 0.f, 0.f};

  uint4 ra = *(const uint4*)Ap;
  uint4 rb0 = *(const uint4*)(Wp);
  uint4 rb1 = *(const uint4*)(Wp + 64 * K_DIM);
  *(uint4*)&As[0][ar * LDA + ac] = ra;
  *(uint4*)&Bs[0][sr * LDA + sc] = rb0;
  *(uint4*)&Bs[0][(sr + 64) * LDA + sc] = rb1;
  ra = *(const uint4*)(Ap + 32);
  rb0 = *(const uint4*)(Wp + 32);
  rb1 = *(const uint4*)(Wp + 64 * K_DIM + 32);
  __syncthreads();

  for (int kt = 0; kt < 16; ++kt) {
    const int cur = kt & 1, nxt = cur ^ 1;
    if (kt < 15) {
      *(uint4*)&As[nxt][ar * LDA + ac] = ra;
      *(uint4*)&Bs[nxt][sr * LDA + sc] = rb0;
      *(uint4*)&Bs[nxt][(sr + 64) * LDA + sc] = rb1;
    }
    if (kt < 14) {
      int ko = (kt + 2) * 32;
      ra = *(const uint4*)(Ap + ko);
      rb0 = *(const uint4*)(Wp + ko);
      rb1 = *(const uint4*)(Wp + 64 * K_DIM + ko);
    }
    bf16x8 af[2], bfr[4];
#pragma unroll
    for (int mi = 0; mi < 2; ++mi)
      af[mi] = *(const bf16x8*)&As[cur][(wm + mi * 16 + l16) * LDA + quad * 8];
#pragma unroll
    for (int ni = 0; ni < 4; ++ni)
      bfr[ni] = *(const bf16x8*)&Bs[cur][(wn + ni * 16 + l16) * LDA + quad * 8];
#pragma unroll
    for (int mi = 0; mi < 2; ++mi)
#pragma unroll
      for (int ni = 0; ni < 4; ++ni)
        acc[mi][ni] = __builtin_amdgcn_mfma_f32_16x16x32_bf16(af[mi], bfr[ni], acc[mi][ni], 0, 0, 0);
    __syncthreads();
  }

#pragma unroll
  for (int ni = 0; ni < 4; ++ni) {
    int f = n0 + wn + ni * 16 + l16;
    float bv = bias[f];
#pragma unroll
    for (int mi = 0; mi < 2; ++mi)
#pragma unroll
      for (int r = 0; r < 4; ++r) {
        int m = m0 + wm + mi * 16 + quad * 4 + r;
        out[(size_t)m * 512 + f] = acc[mi][ni][r] + bv;
      }
  }
}

// ---------------- launcher ----------------
extern "C" void kernel_launch(void* const* d_in, const int* in_sizes, int n_in,
                              void* d_out, int out_size, void* d_ws, size_t ws_size,
                              hipStream_t stream) {
  const float* x1   = (const float*)d_in[0];
  const float* x2   = (const float*)d_in[1];
  const float* qkvw = (const float*)d_in[2];
  const float* qkvb = (const float*)d_in[3];
  const float* outw = (const float*)d_in[4];
  const float* outb = (const float*)d_in[5];
  float* out = (float*)d_out;
  char* ws = (char*)d_ws;

  u16* xb    = (u16*)(ws + 0);          // [8192][512] bf16
  u16* wqkv  = (u16*)(ws + 8388608);    // [1536][512]
  u16* wout  = (u16*)(ws + 9961472);    // [512][512]
  u16* qb    = (u16*)(ws + 10485760);   // [2][2][8][2048][64]
  u16* kb    = (u16*)(ws + 18874368);   // [2][2][8][2048][64]
  u16* vtb   = (u16*)(ws + 27262976);   // [2][2][8][64][2048]
  u16* attnb = (u16*)(ws + 0);          // [8192][512]  (aliases xb)

  cvt_kernel<<<5120, 256, 0, stream>>>(x1, x2, qkvw, outw, xb, wqkv, wout);

  dim3 g1(64, 12);
  qkv_gemm<<<g1, 256, 0, stream>>>(xb, wqkv, qkvb, qb, kb, vtb);

  attn_kernel<<<512, 512, 0, stream>>>(qb, kb, vtb, attnb);

  dim3 g3(128, 4);
  out_gemm<<<g3, 256, 0, stream>>>(attnb, wout, outb, out);
}

// Round 9
// 156.336 us; speedup vs baseline: 1.2401x; 1.0514x over previous
//
#include <hip/hip_runtime.h>
#include <stdint.h>

typedef unsigned short u16;
typedef unsigned int u32;
typedef short bf16x8 __attribute__((ext_vector_type(8)));
typedef float f32x4 __attribute__((ext_vector_type(4)));
typedef float f32x16 __attribute__((ext_vector_type(16)));

#define K_DIM 512

__device__ __forceinline__ u16 f2bf(float f) {
  union { float f; u32 u; } v; v.f = f;
  return (u16)((v.u + 0x8000u) >> 16);  // round-half-up
}
__device__ __forceinline__ u32 pk2(float lo, float hi) {
  union { float f; u32 u; } a, b; a.f = lo; b.f = hi;
  return __builtin_amdgcn_perm(b.u + 0x8000u, a.u + 0x8000u, 0x07060302u);
}

// ---------------- kernel 0: fp32 -> bf16 conversions ----------------
__global__ void cvt_kernel(const float* __restrict__ x1, const float* __restrict__ x2,
                           const float* __restrict__ qkvw, const float* __restrict__ outw,
                           u16* __restrict__ xb, u16* __restrict__ wqkv, u16* __restrict__ wout) {
  int tid = blockIdx.x * 256 + threadIdx.x;
  const float4* src; u16* dst; int idx = tid;
  if (idx < 524288)        { src = (const float4*)x1;   dst = xb; }
  else if (idx < 1048576)  { src = (const float4*)x2;   dst = xb + 2097152; idx -= 524288; }
  else if (idx < 1245184)  { src = (const float4*)qkvw; dst = wqkv;         idx -= 1048576; }
  else                     { src = (const float4*)outw; dst = wout;         idx -= 1245184; }
  float4 v = src[idx];
  *(uint2*)&dst[idx * 4] = make_uint2(pk2(v.x, v.y), pk2(v.z, v.w));
}

#define LDA 40  // BK=32 + 8 pad

// ---------------- kernel 1: QKV GEMM (C^T, dbuf single-barrier) + scatter epilogue ----------------
__global__ __launch_bounds__(256, 3) void qkv_gemm(
    const u16* __restrict__ A, const u16* __restrict__ W, const float* __restrict__ bias,
    u16* __restrict__ qb, u16* __restrict__ kb, u16* __restrict__ vtb) {
  __shared__ __align__(16) u16 As[2][128 * LDA];
  __shared__ __align__(16) u16 Bs[2][128 * LDA];
  const int t = threadIdx.x;
  const int m0 = blockIdx.x * 128, n0 = blockIdx.y * 128;
  const int lane = t & 63, l16 = lane & 15, quad = lane >> 4;
  const int w = t >> 6;
  const int wm = (w >> 1) * 64, wn = (w & 1) * 64;
  const int sr = t >> 2, sc = (t & 3) * 8;

  const u16* Ap = A + (size_t)(m0 + sr) * K_DIM + sc;
  const u16* Wp = W + (size_t)(n0 + sr) * K_DIM + sc;

  f32x4 acc[4][4];
#pragma unroll
  for (int i = 0; i < 4; ++i)
#pragma unroll
    for (int j = 0; j < 4; ++j) acc[i][j] = (f32x4){0.f, 0.f, 0.f, 0.f};

  uint4 ra0 = *(const uint4*)(Ap);
  uint4 ra1 = *(const uint4*)(Ap + 64 * K_DIM);
  uint4 rb0 = *(const uint4*)(Wp);
  uint4 rb1 = *(const uint4*)(Wp + 64 * K_DIM);
  *(uint4*)&As[0][sr * LDA + sc] = ra0;
  *(uint4*)&As[0][(sr + 64) * LDA + sc] = ra1;
  *(uint4*)&Bs[0][sr * LDA + sc] = rb0;
  *(uint4*)&Bs[0][(sr + 64) * LDA + sc] = rb1;
  ra0 = *(const uint4*)(Ap + 32);
  ra1 = *(const uint4*)(Ap + 64 * K_DIM + 32);
  rb0 = *(const uint4*)(Wp + 32);
  rb1 = *(const uint4*)(Wp + 64 * K_DIM + 32);
  __syncthreads();

  for (int kt = 0; kt < 16; ++kt) {
    const int cur = kt & 1, nxt = cur ^ 1;
    if (kt < 15) {
      *(uint4*)&As[nxt][sr * LDA + sc] = ra0;
      *(uint4*)&As[nxt][(sr + 64) * LDA + sc] = ra1;
      *(uint4*)&Bs[nxt][sr * LDA + sc] = rb0;
      *(uint4*)&Bs[nxt][(sr + 64) * LDA + sc] = rb1;
    }
    if (kt < 14) {
      int ko = (kt + 2) * 32;
      ra0 = *(const uint4*)(Ap + ko);
      ra1 = *(const uint4*)(Ap + 64 * K_DIM + ko);
      rb0 = *(const uint4*)(Wp + ko);
      rb1 = *(const uint4*)(Wp + 64 * K_DIM + ko);
    }
    bf16x8 af[4], bfr[4];
#pragma unroll
    for (int mi = 0; mi < 4; ++mi)
      af[mi] = *(const bf16x8*)&As[cur][(wm + mi * 16 + l16) * LDA + quad * 8];
#pragma unroll
    for (int ni = 0; ni < 4; ++ni)
      bfr[ni] = *(const bf16x8*)&Bs[cur][(wn + ni * 16 + l16) * LDA + quad * 8];
#pragma unroll
    for (int mi = 0; mi < 4; ++mi)
#pragma unroll
      for (int ni = 0; ni < 4; ++ni)
        acc[mi][ni] = __builtin_amdgcn_mfma_f32_16x16x32_bf16(bfr[ni], af[mi], acc[mi][ni], 0, 0, 0);
    __syncthreads();
  }

  const int fbase = n0 + wn;
  const int h = fbase / 192;
  const int s = (fbase - h * 192) >> 6;
  float4 bv[4];
#pragma unroll
  for (int ni = 0; ni < 4; ++ni)
    bv[ni] = *(const float4*)&bias[fbase + ni * 16 + quad * 4];
  const int bh = m0 >> 11;
  const int lbase = (m0 & 2047) + wm;

  if (s == 2) {
    u16* dst = vtb + (size_t)((bh * 8 + h) * 64) * 2048;
#pragma unroll
    for (int mi = 0; mi < 4; ++mi) {
      int l = lbase + mi * 16 + l16;
#pragma unroll
      for (int ni = 0; ni < 4; ++ni)
#pragma unroll
        for (int r = 0; r < 4; ++r)
          dst[(ni * 16 + quad * 4 + r) * 2048 + l] = f2bf(acc[mi][ni][r] + bv[ni][r]);
    }
  } else {
    u16* dst = (s == 0 ? qb : kb) + (size_t)((bh * 8 + h) * 2048) * 64;
    const float sc2 = (s == 0) ? 0.18033688011112042f : 1.0f;
#pragma unroll
    for (int mi = 0; mi < 4; ++mi) {
      int l = lbase + mi * 16 + l16;
#pragma unroll
      for (int ni = 0; ni < 4; ++ni) {
        float v0 = (acc[mi][ni][0] + bv[ni][0]) * sc2;
        float v1 = (acc[mi][ni][1] + bv[ni][1]) * sc2;
        float v2 = (acc[mi][ni][2] + bv[ni][2]) * sc2;
        float v3 = (acc[mi][ni][3] + bv[ni][3]) * sc2;
        *(uint2*)&dst[(size_t)l * 64 + ni * 16 + quad * 4] = make_uint2(pk2(v0, v1), pk2(v2, v3));
      }
    }
  }
}

// ---------------- kernel 2: flash cross-attention (S^T, 32x32x16 MFMA) ----------------
// grid 512: 128 q-rows/block, 4 waves x 32 q-rows (32x32 tiles); K-tiles of 64.
// Per-wave-iter LDS: 8 A-frag (S) + 8 A-frag (PV) + 4 P-read + 8 P-b64-write = 24 KB / 32 qrows.
// XCD swizzle: comb = bid&31 -> all 16 q-tiles of a (pair,b,h) land on one XCD (K/V in its L2).
// LDS: Ks 64x72 (9216) + VTs 64x72 (9216) + Ps 128x72 (18432) = 36864 B.
// 32x32x16 layouts: C/D col=lane&31, row=(reg&3)+8*(reg>>2)+4*(lane>>5) [m101-verified];
// A[m=lane&31][k=(lane>>5)*8+j], B[k=(lane>>5)*8+j][n=lane&31] (analogous to verified 16x16 map).
#define LQ 72
#define LP 72

__global__ __launch_bounds__(256, 2) void attn_kernel(
    const u16* __restrict__ qb, const u16* __restrict__ kb, const u16* __restrict__ vtb,
    u16* __restrict__ attnb) {
  __shared__ __align__(16) u16 Ks[64 * LQ];    // [kcol][d]
  __shared__ __align__(16) u16 VTs[64 * LQ];   // [d][kcol]
  __shared__ __align__(16) u16 Ps[128 * LP];   // Q staging [qrow][d], then per-wave P [qrow][kcol]

  const int t = threadIdx.x;
  const int w = t >> 6, lane = t & 63, l32 = lane & 31, h2 = lane >> 5;
  const int bid = blockIdx.x;
  const int comb = bid & 31;        // XCD swizzle: same comb -> same bid%8 -> same XCD
  const int qt = bid >> 5;
  const int h = comb & 7, bb = (comb >> 3) & 1, pair = comb >> 4;
  const int in_q = pair, in_kv = pair ^ 1;

  const u16* Qg = qb + (size_t)((in_q * 2 + bb) * 8 + h) * 2048 * 64;
  const u16* Kg = kb + (size_t)((in_kv * 2 + bb) * 8 + h) * 2048 * 64;
  const u16* Vg = vtb + (size_t)((in_kv * 2 + bb) * 8 + h) * 64 * 2048;

  // stage Q [128][64] into Ps (stride LP): 1024 uint4, 4 per thread
#pragma unroll
  for (int u = 0; u < 4; ++u) {
    int idx = u * 256 + t;
    int row = idx >> 3, seg = (idx & 7) * 8;
    *(uint4*)&Ps[row * LP + seg] = *(const uint4*)(Qg + (qt * 128 + row) * 64 + seg);
  }
  // prefetch K/V tile 0 (64x64 each): 2 uint4 per thread per array
  const int srow = t >> 3, sseg = (t & 7) * 8;   // rows 0..31 (+32)
  uint4 rk0 = *(const uint4*)(Kg + srow * 64 + sseg);
  uint4 rk1 = *(const uint4*)(Kg + (srow + 32) * 64 + sseg);
  uint4 rv0 = *(const uint4*)(Vg + srow * 2048 + sseg);
  uint4 rv1 = *(const uint4*)(Vg + (srow + 32) * 2048 + sseg);
  __syncthreads();   // Q staged & visible

  // hoist Q B-frags: wave w owns qrows w*32..+31 (same Ps rows reused as its P buffer)
  bf16x8 qf[4];
#pragma unroll
  for (int ks = 0; ks < 4; ++ks)
    qf[ks] = *(const bf16x8*)&Ps[(w * 32 + l32) * LP + ks * 16 + h2 * 8];

  f32x16 oacc[2];
#pragma unroll
  for (int mi = 0; mi < 2; ++mi)
#pragma unroll
    for (int r = 0; r < 16; ++r) oacc[mi][r] = 0.f;
  float rs = 0.f;

  u16* Pw = &Ps[w * 32 * LP];   // wave-private P rows [32][LP]

  for (int kt = 0; kt < 32; ++kt) {
    // stage current tile (prev readers finished at bottom barrier)
    *(uint4*)&Ks[srow * LQ + sseg] = rk0;
    *(uint4*)&Ks[(srow + 32) * LQ + sseg] = rk1;
    *(uint4*)&VTs[srow * LQ + sseg] = rv0;
    *(uint4*)&VTs[(srow + 32) * LQ + sseg] = rv1;
    __syncthreads();
    if (kt < 31) {
      int ko = (kt + 1) * 64;
      rk0 = *(const uint4*)(Kg + (ko + srow) * 64 + sseg);
      rk1 = *(const uint4*)(Kg + (ko + srow + 32) * 64 + sseg);
      rv0 = *(const uint4*)(Vg + srow * 2048 + ko + sseg);
      rv1 = *(const uint4*)(Vg + (srow + 32) * 2048 + ko + sseg);
    }

    // S^T[kcol 64][qrow 32] = K (A) . Q (B): 2 m-tiles x 4 k-steps
    f32x16 sacc[2];
#pragma unroll
    for (int mi = 0; mi < 2; ++mi)
#pragma unroll
      for (int r = 0; r < 16; ++r) sacc[mi][r] = 0.f;
#pragma unroll
    for (int ks = 0; ks < 4; ++ks) {
      bf16x8 kfr0 = *(const bf16x8*)&Ks[(l32) * LQ + ks * 16 + h2 * 8];
      bf16x8 kfr1 = *(const bf16x8*)&Ks[(32 + l32) * LQ + ks * 16 + h2 * 8];
      sacc[0] = __builtin_amdgcn_mfma_f32_32x32x16_bf16(kfr0, qf[ks], sacc[0], 0, 0, 0);
      sacc[1] = __builtin_amdgcn_mfma_f32_32x32x16_bf16(kfr1, qf[ks], sacc[1], 0, 0, 0);
    }

    // p = exp2(s); lane's reg-group rg = 4 consecutive kcols of qrow l32 -> b64 writes
#pragma unroll
    for (int mi = 0; mi < 2; ++mi)
#pragma unroll
      for (int rg = 0; rg < 4; ++rg) {
        float p0 = __builtin_amdgcn_exp2f(sacc[mi][rg * 4 + 0]);
        float p1 = __builtin_amdgcn_exp2f(sacc[mi][rg * 4 + 1]);
        float p2 = __builtin_amdgcn_exp2f(sacc[mi][rg * 4 + 2]);
        float p3 = __builtin_amdgcn_exp2f(sacc[mi][rg * 4 + 3]);
        rs += (p0 + p1) + (p2 + p3);
        *(uint2*)&Pw[l32 * LP + mi * 32 + rg * 8 + h2 * 4] = make_uint2(pk2(p0, p1), pk2(p2, p3));
      }

    // O^T[d 64][qrow 32] += V^T (A) . P (B)
#pragma unroll
    for (int ks = 0; ks < 4; ++ks) {
      bf16x8 pf = *(const bf16x8*)&Pw[l32 * LP + ks * 16 + h2 * 8];
      bf16x8 vf0 = *(const bf16x8*)&VTs[(l32) * LQ + ks * 16 + h2 * 8];
      bf16x8 vf1 = *(const bf16x8*)&VTs[(32 + l32) * LQ + ks * 16 + h2 * 8];
      oacc[0] = __builtin_amdgcn_mfma_f32_32x32x16_bf16(vf0, pf, oacc[0], 0, 0, 0);
      oacc[1] = __builtin_amdgcn_mfma_f32_32x32x16_bf16(vf1, pf, oacc[1], 0, 0, 0);
    }
    __syncthreads();   // all waves done reading Ks/VTs; next iter may overwrite
  }

  // epilogue: qrow = w*32 + l32 owned by lanes (l32, l32+32) with complementary kcol/d sets
  rs += __shfl_xor(rs, 32);
  const float inv = 1.0f / rs;
  const int row = in_q * 4096 + bb * 2048 + qt * 128 + w * 32 + l32;
#pragma unroll
  for (int mi = 0; mi < 2; ++mi)
#pragma unroll
    for (int rg = 0; rg < 4; ++rg) {
      float v0 = oacc[mi][rg * 4 + 0] * inv;
      float v1 = oacc[mi][rg * 4 + 1] * inv;
      float v2 = oacc[mi][rg * 4 + 2] * inv;
      float v3 = oacc[mi][rg * 4 + 3] * inv;
      *(uint2*)&attnb[(size_t)row * 512 + h * 64 + mi * 32 + rg * 8 + h2 * 4] =
          make_uint2(pk2(v0, v1), pk2(v2, v3));
    }
}

// ---------------- kernel 3: output projection (64x128 tiles, dbuf) ----------------
__global__ __launch_bounds__(256, 2) void out_gemm(
    const u16* __restrict__ A, const u16* __restrict__ W, const float* __restrict__ bias,
    float* __restrict__ out) {
  __shared__ __align__(16) u16 As[2][64 * LDA];
  __shared__ __align__(16) u16 Bs[2][128 * LDA];
  const int t = threadIdx.x;
  const int m0 = blockIdx.x * 64, n0 = blockIdx.y * 128;
  const int lane = t & 63, l16 = lane & 15, quad = lane >> 4;
  const int w = t >> 6;
  const int wm = (w & 1) * 32, wn = (w >> 1) * 64;
  const int ar = t >> 2, ac = (t & 3) * 8;
  const int sr = t >> 2, sc = (t & 3) * 8;

  const u16* Ap = A + (size_t)(m0 + ar) * K_DIM + ac;
  const u16* Wp = W + (size_t)(n0 + sr) * K_DIM + sc;

  f32x4 acc[2][4];
#pragma unroll
  for (int i = 0; i < 2; ++i)
#pragma unroll
    for (int j = 0; j < 4; ++j) acc[i][j] = (f32x4){0.f, 0.f, 0.f, 0.f};

  uint4 ra = *(const uint4*)Ap;
  uint4 rb0 = *(const uint4*)(Wp);
  uint4 rb1 = *(const uint4*)(Wp + 64 * K_DIM);
  *(uint4*)&As[0][ar * LDA + ac] = ra;
  *(uint4*)&Bs[0][sr * LDA + sc] = rb0;
  *(uint4*)&Bs[0][(sr + 64) * LDA + sc] = rb1;
  ra = *(const uint4*)(Ap + 32);
  rb0 = *(const uint4*)(Wp + 32);
  rb1 = *(const uint4*)(Wp + 64 * K_DIM + 32);
  __syncthreads();

  for (int kt = 0; kt < 16; ++kt) {
    const int cur = kt & 1, nxt = cur ^ 1;
    if (kt < 15) {
      *(uint4*)&As[nxt][ar * LDA + ac] = ra;
      *(uint4*)&Bs[nxt][sr * LDA + sc] = rb0;
      *(uint4*)&Bs[nxt][(sr + 64) * LDA + sc] = rb1;
    }
    if (kt < 14) {
      int ko = (kt + 2) * 32;
      ra = *(const uint4*)(Ap + ko);
      rb0 = *(const uint4*)(Wp + ko);
      rb1 = *(const uint4*)(Wp + 64 * K_DIM + ko);
    }
    bf16x8 af[2], bfr[4];
#pragma unroll
    for (int mi = 0; mi < 2; ++mi)
      af[mi] = *(const bf16x8*)&As[cur][(wm + mi * 16 + l16) * LDA + quad * 8];
#pragma unroll
    for (int ni = 0; ni < 4; ++ni)
      bfr[ni] = *(const bf16x8*)&Bs[cur][(wn + ni * 16 + l16) * LDA + quad * 8];
#pragma unroll
    for (int mi = 0; mi < 2; ++mi)
#pragma unroll
      for (int ni = 0; ni < 4; ++ni)
        acc[mi][ni] = __builtin_amdgcn_mfma_f32_16x16x32_bf16(af[mi], bfr[ni], acc[mi][ni], 0, 0, 0);
    __syncthreads();
  }

#pragma unroll
  for (int ni = 0; ni < 4; ++ni) {
    int f = n0 + wn + ni * 16 + l16;
    float bv = bias[f];
#pragma unroll
    for (int mi = 0; mi < 2; ++mi)
#pragma unroll
      for (int r = 0; r < 4; ++r) {
        int m = m0 + wm + mi * 16 + quad * 4 + r;
        out[(size_t)m * 512 + f] = acc[mi][ni][r] + bv;
      }
  }
}

// ---------------- launcher ----------------
extern "C" void kernel_launch(void* const* d_in, const int* in_sizes, int n_in,
                              void* d_out, int out_size, void* d_ws, size_t ws_size,
                              hipStream_t stream) {
  const float* x1   = (const float*)d_in[0];
  const float* x2   = (const float*)d_in[1];
  const float* qkvw = (const float*)d_in[2];
  const float* qkvb = (const float*)d_in[3];
  const float* outw = (const float*)d_in[4];
  const float* outb = (const float*)d_in[5];
  float* out = (float*)d_out;
  char* ws = (char*)d_ws;

  u16* xb    = (u16*)(ws + 0);          // [8192][512] bf16
  u16* wqkv  = (u16*)(ws + 8388608);    // [1536][512]
  u16* wout  = (u16*)(ws + 9961472);    // [512][512]
  u16* qb    = (u16*)(ws + 10485760);   // [2][2][8][2048][64]
  u16* kb    = (u16*)(ws + 18874368);   // [2][2][8][2048][64]
  u16* vtb   = (u16*)(ws + 27262976);   // [2][2][8][64][2048]
  u16* attnb = (u16*)(ws + 0);          // [8192][512]  (aliases xb)

  cvt_kernel<<<5120, 256, 0, stream>>>(x1, x2, qkvw, outw, xb, wqkv, wout);

  dim3 g1(64, 12);
  qkv_gemm<<<g1, 256, 0, stream>>>(xb, wqkv, qkvb, qb, kb, vtb);

  attn_kernel<<<512, 256, 0, stream>>>(qb, kb, vtb, attnb);

  dim3 g3(128, 4);
  out_gemm<<<g3, 256, 0, stream>>>(attnb, wout, outb, out);
}